// Round 2
// baseline (138.288 us; speedup 1.0000x reference)
//
#include <hip/hip_runtime.h>

// Problem constants
#define B_   16
#define C_   512
#define N_   1024   // H*W
#define F_   1024
#define T_   180
#define G_   32

// Workspace layout (float offsets)
#define WS_MU    0                    // 512  (B*G)
#define WS_RSIG  512                  // 512
#define WS_K     1024                 // 16384 (B*F)
#define WS_V     (1024 + 16384)       // 16384
#define WS_WQS   (1024 + 2*16384)     // 512
#define WS_WOS   (WS_WQS + 512)       // 512
#define WS_BQS   (WS_WOS + 512)       // 1     -> total 34817 floats (~136 KB)

// ---------------------------------------------------------------------------
// Kernel 1: group-norm stats + K/V projections + weight column/row sums
//   blocks [0,512)  : per-(b,g) mean/rsig over 16*1024 contiguous floats
//   blocks [512,576): K[b,f], V[b,f]
//   blocks [576,578): WQsum[c] = sum_o wq[o,c]
//   blocks [578,580): WOsum[o] = sum_c wo[o,c]
//   block  580      : BQsum = sum_c bq[c]
// ---------------------------------------------------------------------------
__global__ __launch_bounds__(256) void k_prep(
    const float* __restrict__ x, const float* __restrict__ cond,
    const float* __restrict__ wq, const float* __restrict__ bq,
    const float* __restrict__ wk, const float* __restrict__ bk,
    const float* __restrict__ wv, const float* __restrict__ bv,
    const float* __restrict__ wo, float* __restrict__ ws)
{
    const int blk = blockIdx.x;
    const int tid = threadIdx.x;

    if (blk < 512) {
        // ---- group stats: 16384 contiguous floats per (b,g) ----
        const float4* xv = (const float4*)(x + (size_t)blk * 16384);
        float s = 0.f, sq = 0.f;
        #pragma unroll
        for (int j = 0; j < 16; ++j) {
            float4 p = xv[tid + (j << 8)];
            s  += (p.x + p.y) + (p.z + p.w);
            sq += p.x * p.x + p.y * p.y + p.z * p.z + p.w * p.w;
        }
        #pragma unroll
        for (int off = 32; off; off >>= 1) {
            s  += __shfl_down(s,  off, 64);
            sq += __shfl_down(sq, off, 64);
        }
        __shared__ float rs[4], rq[4];
        if ((tid & 63) == 0) { rs[tid >> 6] = s; rq[tid >> 6] = sq; }
        __syncthreads();
        if (tid == 0) {
            float S1 = rs[0] + rs[1] + rs[2] + rs[3];
            float S2 = rq[0] + rq[1] + rq[2] + rq[3];
            float mu = S1 * (1.f / 16384.f);
            float var = S2 * (1.f / 16384.f) - mu * mu;
            ws[WS_MU + blk]   = mu;
            ws[WS_RSIG + blk] = rsqrtf(var + 1e-6f);
        }
    } else if (blk < 576) {
        // ---- K/V: one thread per f; cond row staged in LDS ----
        const int idx = blk - 512;          // [0,64)
        const int b   = idx >> 2;
        const int f   = ((idx & 3) << 8) + tid;
        __shared__ float condl[T_];
        if (tid < T_) condl[tid] = cond[b * T_ + tid];
        __syncthreads();
        float accK = bk[f];
        float accV = bv[f];
        const float* wkr = wk + f * T_;
        const float* wvr = wv + f * T_;
        #pragma unroll 4
        for (int t = 0; t < T_; ++t) {
            float cf = condl[t];
            accK += cf * wkr[t];
            accV += cf * wvr[t];
        }
        ws[WS_K + b * F_ + f] = accK;
        ws[WS_V + b * F_ + f] = accV;
    } else if (blk < 578) {
        // ---- WQsum[c] = sum_o wq[o*512+c] ----
        const int c = ((blk - 576) << 8) + tid;
        float acc = 0.f;
        for (int o = 0; o < C_; ++o) acc += wq[o * C_ + c];
        ws[WS_WQS + c] = acc;
    } else if (blk < 580) {
        // ---- WOsum[o] = sum_c wo[o*512+c] (row-contiguous, 16B vec) ----
        const int o = ((blk - 578) << 8) + tid;
        const float4* row = (const float4*)(wo + o * C_);
        float acc = 0.f;
        #pragma unroll 8
        for (int j = 0; j < 128; ++j) {
            float4 p = row[j];
            acc += (p.x + p.y) + (p.z + p.w);
        }
        ws[WS_WOS + o] = acc;
    } else {
        // ---- BQsum ----
        float p = bq[tid] + bq[tid + 256];
        #pragma unroll
        for (int off = 32; off; off >>= 1) p += __shfl_down(p, off, 64);
        __shared__ float rb[4];
        if ((tid & 63) == 0) rb[tid >> 6] = p;
        __syncthreads();
        if (tid == 0) ws[WS_BQS] = rb[0] + rb[1] + rb[2] + rb[3];
    }
}

// ---------------------------------------------------------------------------
// Kernel 2 (fused): per (b, 32-n tile):
//   S[n]   = sum_c x[b,c,n]*coef[b,c] + offset[b]
//   A[n]   = sum_f V[b,f]*softmax_f(scale*S[n]*K[b,f])   (analytic max: K extremum)
//   out[b,o,n] = x[b,o,n] + A[n]*WOsum[o] + bo[o]
// Grid: 512 blocks = 16 b x 32 n-tiles; 256 threads.
// ---------------------------------------------------------------------------
__global__ __launch_bounds__(256) void k_fused(
    const float* __restrict__ x, const float* __restrict__ gamma,
    const float* __restrict__ beta, const float* __restrict__ bo,
    const float* __restrict__ ws, float* __restrict__ out)
{
    const int b   = blockIdx.x >> 5;
    const int n0  = (blockIdx.x & 31) << 5;
    const int tid = threadIdx.x;

    __shared__ float coef[C_];
    __shared__ float KV[2 * F_];
    __shared__ float part[8][32];
    __shared__ float pse[8][32], psv[8][32];
    __shared__ float Sl[32], Al[32];
    __shared__ float opw[4], redmx[4], redmn[4];

    // ---- Phase A: coef/offset + K/V staging + K extrema ----
    float op = 0.f;
    #pragma unroll
    for (int c = tid; c < C_; c += 256) {
        const int g = c >> 4;
        float rsig = ws[WS_RSIG + b * G_ + g];
        float mu   = ws[WS_MU   + b * G_ + g];
        float gm   = gamma[c];
        float wqs  = ws[WS_WQS + c];
        coef[c] = rsig * gm * wqs;
        op += (beta[c] - mu * rsig * gm) * wqs;
    }
    const float* Kg = ws + WS_K + b * F_;
    const float* Vg = ws + WS_V + b * F_;
    float mx = -1e30f, mn = 1e30f;
    #pragma unroll
    for (int i = tid; i < F_; i += 256) {
        float kv = Kg[i];
        KV[2 * i]     = kv;
        KV[2 * i + 1] = Vg[i];
        mx = fmaxf(mx, kv);
        mn = fminf(mn, kv);
    }
    #pragma unroll
    for (int off = 32; off; off >>= 1) {
        op += __shfl_down(op, off, 64);
        mx = fmaxf(mx, __shfl_down(mx, off, 64));
        mn = fminf(mn, __shfl_down(mn, off, 64));
    }
    if ((tid & 63) == 0) {
        opw[tid >> 6]   = op;
        redmx[tid >> 6] = mx;
        redmn[tid >> 6] = mn;
    }
    __syncthreads();
    const float offset = ws[WS_BQS] + opw[0] + opw[1] + opw[2] + opw[3];
    const float maxK = fmaxf(fmaxf(redmx[0], redmx[1]), fmaxf(redmx[2], redmx[3]));
    const float minK = fminf(fminf(redmn[0], redmn[1]), fminf(redmn[2], redmn[3]));

    // ---- Phase B: S over the tile ----
    const int nl = tid & 31;
    const int cq = tid >> 5;              // 0..7, 64 channels each
    {
        const float* xp = x + (((b * C_ + (cq << 6)) << 10) + n0 + nl);
        float acc = 0.f;
        #pragma unroll 8
        for (int ci = 0; ci < 64; ++ci) {
            acc += xp[ci << 10] * coef[(cq << 6) + ci];
        }
        part[cq][nl] = acc;
    }
    __syncthreads();
    if (tid < 32) {
        float s8 = 0.f;
        #pragma unroll
        for (int j = 0; j < 8; ++j) s8 += part[j][tid];
        Sl[tid] = s8 + offset;
    }
    __syncthreads();

    // ---- Phase C: rank-1 softmax over f ----
    const float LOG2E = 1.4426950408889634f;
    const float scale = 0.044194173824159216f;   // 512^-0.5
    const float s  = Sl[nl] * scale;
    const float sl = s * LOG2E;
    const float ml = (s >= 0.f ? maxK : minK) * sl;   // log2-domain row max

    float se = 0.f, sv = 0.f;
    const int fq = tid >> 5;              // 0..7, 128 f each
    const int fbase = fq << 7;
    #pragma unroll 8
    for (int fi = 0; fi < 128; ++fi) {
        const int f = fbase + fi;
        float kf = KV[2 * f];
        float vf = KV[2 * f + 1];
        float e = exp2f(fmaf(sl, kf, -ml));
        se += e;
        sv = fmaf(vf, e, sv);
    }
    pse[fq][nl] = se;
    psv[fq][nl] = sv;
    __syncthreads();
    if (tid < 32) {
        float den = 0.f, num = 0.f;
        #pragma unroll
        for (int j = 0; j < 8; ++j) { den += pse[j][tid]; num += psv[j][tid]; }
        Al[tid] = num / den;
    }
    __syncthreads();

    // ---- Phase D: residual + projected-out write (float4 along n) ----
    const int col = tid & 7;    // n4-group: n-offset col*4
    const int row = tid >> 3;   // 0..31
    float av[4];
    #pragma unroll
    for (int j = 0; j < 4; ++j) av[j] = Al[(col << 2) + j];
    const float* WOS = ws + WS_WOS;

    for (int p = 0; p < 16; ++p) {
        const int o = (p << 5) + row;
        const float w   = WOS[o];
        const float bof = bo[o];
        const size_t base = (((size_t)(b * C_ + o)) << 10) + n0 + (col << 2);
        float4 xv = *(const float4*)(x + base);
        float4 ov;
        ov.x = xv.x + fmaf(av[0], w, bof);
        ov.y = xv.y + fmaf(av[1], w, bof);
        ov.z = xv.z + fmaf(av[2], w, bof);
        ov.w = xv.w + fmaf(av[3], w, bof);
        *(float4*)(out + base) = ov;
    }
}

extern "C" void kernel_launch(void* const* d_in, const int* in_sizes, int n_in,
                              void* d_out, int out_size, void* d_ws, size_t ws_size,
                              hipStream_t stream) {
    const float* x     = (const float*)d_in[0];
    const float* cond  = (const float*)d_in[1];
    const float* gamma = (const float*)d_in[2];
    const float* beta  = (const float*)d_in[3];
    const float* wq    = (const float*)d_in[4];
    const float* bq    = (const float*)d_in[5];
    const float* wk    = (const float*)d_in[6];
    const float* bk    = (const float*)d_in[7];
    const float* wv    = (const float*)d_in[8];
    const float* bv    = (const float*)d_in[9];
    const float* wo    = (const float*)d_in[10];
    const float* bo    = (const float*)d_in[11];
    float* ws  = (float*)d_ws;
    float* out = (float*)d_out;

    hipLaunchKernelGGL(k_prep, dim3(581), dim3(256), 0, stream,
                       x, cond, wq, bq, wk, bk, wv, bv, wo, ws);
    hipLaunchKernelGGL(k_fused, dim3(512), dim3(256), 0, stream,
                       x, gamma, beta, bo, ws, out);
}